// Round 6
// baseline (680.681 us; speedup 1.0000x reference)
//
#include <hip/hip_runtime.h>
#include <hip/hip_bf16.h>

// Problem constants
#define BB 16
#define SS 128
#define DD 128
#define EE 64
#define TT 128
#define NN (BB*SS)      // 2048 tokens
#define KSPLIT 16       // K split for the big GEMM (d-chunks of 8)

typedef __attribute__((ext_vector_type(8))) short short8;
typedef __attribute__((ext_vector_type(4))) float f32x4;
typedef __attribute__((ext_vector_type(4))) unsigned int u32x4;

__device__ inline unsigned pkbf16(float a, float b) {
    unsigned r;
    asm volatile("v_cvt_pk_bf16_f32 %0, %1, %2" : "=v"(r) : "v"(a), "v"(b));
    return r;
}
__device__ inline float bflo(unsigned u) { return __builtin_bit_cast(float, (unsigned)(u << 16)); }
__device__ inline float bfhi(unsigned u) { return __builtin_bit_cast(float, (unsigned)(u & 0xffff0000u)); }

#define LDS_SWZ(row, bcol) ((row) * 256 + ((bcol) ^ (((row) & 7) << 4)))

// ---------------- fused prep: g1 (256 blk) + w2b (1024 blk) + gather (1024 blk) + basics (1 blk) ----------------
__global__ __launch_bounds__(256) void k_prep(const float* __restrict__ W1,
                                              const float* __restrict__ dep_table,
                                              const float* __restrict__ W2,
                                              const float* __restrict__ token_table,
                                              const int* __restrict__ tokens,
                                              const float* __restrict__ b2,
                                              const float* __restrict__ wr,
                                              const float* __restrict__ br,
                                              __hip_bfloat16* __restrict__ G1,
                                              __hip_bfloat16* __restrict__ W2b,
                                              float* __restrict__ tok,
                                              float* __restrict__ basics,
                                              unsigned* __restrict__ state) {
    int bid = blockIdx.x;
    int tid = threadIdx.x;
    if (bid == 0 && tid == 0) { state[0] = 0u; state[1] = 0u; }  // grid-barrier init (poisoned 0xAA otherwise)
    if (bid < 256) {
        // --- G1[v][t][d] = sum_e W1[t][d][e]*dep_table[v][e] (bf16), no spills ---
        int bx = bid & 63, by = bid >> 6;
        int td = bx * 256 + tid;      // t*128 + d
        int v0 = by * 16;             // v-chunk
        const float* w1row = W1 + (size_t)td * 64;
        float acc[16] = {};
#pragma unroll
        for (int e0 = 0; e0 < 64; e0 += 8) {
            f32x4 wa = *(const f32x4*)(w1row + e0);
            f32x4 wb = *(const f32x4*)(w1row + e0 + 4);
#pragma unroll
            for (int v = 0; v < 16; v++) {
                const float* dr = dep_table + (v0 + v) * 64 + e0;  // wave-uniform -> s_load
                acc[v] += wa[0] * dr[0] + wa[1] * dr[1] + wa[2] * dr[2] + wa[3] * dr[3]
                        + wb[0] * dr[4] + wb[1] * dr[5] + wb[2] * dr[6] + wb[3] * dr[7];
            }
        }
#pragma unroll
        for (int v = 0; v < 16; v++)
            G1[(size_t)(v0 + v) * (TT * DD) + td] = __float2bfloat16(acc[v]);
    } else if (bid < 1280) {
        // --- W2b pre-swizzled bf16: per d, [p=128][256B row], slot s holds t-range (s^(p&7)) ---
        int cid = (bid - 256) * 256 + tid;  // 262144 chunks of 16B
        int d = cid >> 11;
        int rem = cid & 2047;
        int p = rem >> 4;
        int sp = rem & 15;
        int h = sp >> 3, s = sp & 7;
        int t0 = h * 64 + ((s ^ (p & 7))) * 8;
        const float* src = W2 + ((size_t)p * 128 + d) * 128 + t0;  // W2[p][d][t]
        f32x4 a = *(const f32x4*)(src);
        f32x4 b = *(const f32x4*)(src + 4);
        u32x4 o;
        o[0] = pkbf16(a[0], a[1]);
        o[1] = pkbf16(a[2], a[3]);
        o[2] = pkbf16(b[0], b[1]);
        o[3] = pkbf16(b[2], b[3]);
        *(u32x4*)((char*)W2b + (size_t)cid * 16) = o;
    } else if (bid < 2304) {
        // --- gather tok ---
        int gid = (bid - 1280) * 256 + tid;  // 2048*128
        int n = gid >> 7, dcol = gid & 127;
        tok[gid] = token_table[(size_t)tokens[n] * 128 + dcol];
    } else {
        // --- basics: c_bg[p], base[p] ---
        __shared__ float red[128];
        int t = tid;
        if (t < 128) red[t] = wr[t];
        __syncthreads();
        for (int s = 64; s > 0; s >>= 1) {
            if (t < s) red[t] += red[t + s];
            __syncthreads();
        }
        if (t < 128) {
            float swr = red[0];
            float cbg = tanhf(b2[t]);
            basics[t] = cbg;                     // c_bg[p]
            basics[128 + t] = swr * cbg + br[0]; // base[p]
        }
    }
}

// ---------------- device-scope grid barrier (sense/generation counter) ----------------
__device__ inline void grid_barrier(unsigned* st, unsigned nblk) {
    __syncthreads();
    if (threadIdx.x == 0) {
        __threadfence();  // flush this block's writes device-wide (cross-XCD)
        unsigned gen = __hip_atomic_load(&st[1], __ATOMIC_ACQUIRE, __HIP_MEMORY_SCOPE_AGENT);
        unsigned arr = __hip_atomic_fetch_add(&st[0], 1u, __ATOMIC_ACQ_REL, __HIP_MEMORY_SCOPE_AGENT);
        if (arr == nblk - 1u) {
            __hip_atomic_store(&st[0], 0u, __ATOMIC_RELAXED, __HIP_MEMORY_SCOPE_AGENT);
            __hip_atomic_fetch_add(&st[1], 1u, __ATOMIC_RELEASE, __HIP_MEMORY_SCOPE_AGENT);
        } else {
            while (__hip_atomic_load(&st[1], __ATOMIC_ACQUIRE, __HIP_MEMORY_SCOPE_AGENT) == gen)
                __builtin_amdgcn_s_sleep(2);
        }
        __threadfence();  // invalidate stale caches before reading others' data
    }
    __syncthreads();
}

// ---------------- persistent mega-kernel: 2 x (tde -> gemm -> e1 -> e2) with grid barriers ----------------
// 48KB LDS + launch_bounds(256,2) -> guaranteed 2 blocks/CU co-resident at grid=512.
__global__ __launch_bounds__(256, 2) void k_mega(const int* __restrict__ dep_types,
                                                 const float* __restrict__ b1,
                                                 const __hip_bfloat16* __restrict__ G1,
                                                 const __hip_bfloat16* __restrict__ W2b,
                                                 float* __restrict__ tok,
                                                 float* __restrict__ tde,
                                                 float* __restrict__ part,
                                                 float* __restrict__ delta,
                                                 const float* __restrict__ basics,
                                                 const float* __restrict__ wr,
                                                 const float* __restrict__ b2,
                                                 const int* __restrict__ heads,
                                                 float* __restrict__ out,
                                                 unsigned* __restrict__ state) {
    __shared__ char smem[49152];
    char* As = smem;            // gemm A tile [64][256B] swizzled
    char* Bs = smem + 16384;    // gemm B tile [128][256B] swizzled
    int* hs  = (int*)smem;      // e2 head rows (2x128)

    const int tid = threadIdx.x;
    const unsigned NBLK = gridDim.x;

    for (int depth = 0; depth < 2; depth++) {
        // ---- phase 1: tde[n][t] = tanh(sum_d tok[n][d]*G1[v][t][d] + b1[t]) ----
        {
            int t = tid & 127;
            int half = tid >> 7;
            for (int u = blockIdx.x; u < 1024; u += (int)NBLK) {
                int n = u * 2 + half;
                int v = dep_types[n];
                const float* trow = tok + (size_t)n * 128;  // wave-uniform row
                const unsigned* g = (const unsigned*)(G1 + (size_t)v * (TT * DD) + t * 128);
                float acc = b1[t];
#pragma unroll
                for (int i = 0; i < 16; i++) {
                    u32x4 w = *(const u32x4*)(g + i * 4);
                    acc += trow[i * 8 + 0] * bflo(w[0]) + trow[i * 8 + 1] * bfhi(w[0]);
                    acc += trow[i * 8 + 2] * bflo(w[1]) + trow[i * 8 + 3] * bfhi(w[1]);
                    acc += trow[i * 8 + 4] * bflo(w[2]) + trow[i * 8 + 5] * bfhi(w[2]);
                    acc += trow[i * 8 + 6] * bflo(w[3]) + trow[i * 8 + 7] * bfhi(w[3]);
                }
                tde[(size_t)n * 128 + t] = tanhf(acc);
            }
        }
        grid_barrier(state, NBLK);

        // ---- phase 2: gemm part[ks][n][p] over 512 units (32 nb x 16 ks), BM=64 ----
        {
            int lane = tid & 63, w = tid >> 6;
            int wm = w >> 1, wp = w & 1;
            int lrow = lane & 15, lk = lane >> 4;
            int r = tid >> 2, q = tid & 3;
            for (int u = blockIdx.x; u < 512; u += (int)NBLK) {
                int nbt = u >> 4, ks = u & 15;
                int n0 = nbt * 64, d0 = ks * 8;
                f32x4 acc[2][4] = {};
                for (int dd = 0; dd < 8; dd++) {
                    int d = d0 + dd;
                    const char* bsrc = (const char*)W2b + (size_t)d * 32768;
#pragma unroll
                    for (int i = 0; i < 8; i++) {
                        int off = (i * 256 + tid) * 16;
                        *(u32x4*)(Bs + off) = *(const u32x4*)(bsrc + off);
                    }
                    float tokv = tok[(size_t)(n0 + r) * 128 + d];
                    const float* trow = tde + (size_t)(n0 + r) * 128 + q * 32;
#pragma unroll
                    for (int s = 0; s < 4; s++) {
                        f32x4 x = *(const f32x4*)(trow + s * 8);
                        f32x4 y = *(const f32x4*)(trow + s * 8 + 4);
                        u32x4 val;
                        val[0] = pkbf16(x[0] * tokv, x[1] * tokv);
                        val[1] = pkbf16(x[2] * tokv, x[3] * tokv);
                        val[2] = pkbf16(y[0] * tokv, y[1] * tokv);
                        val[3] = pkbf16(y[2] * tokv, y[3] * tokv);
                        int bcol = q * 64 + s * 16;
                        *(u32x4*)(As + LDS_SWZ(r, bcol)) = val;
                    }
                    __syncthreads();
#pragma unroll
                    for (int kk = 0; kk < 4; kk++) {
                        short8 aF[2], bF[4];
#pragma unroll
                        for (int mi = 0; mi < 2; mi++) {
                            int row = wm * 32 + mi * 16 + lrow;
                            aF[mi] = *(const short8*)(As + LDS_SWZ(row, kk * 64 + lk * 16));
                        }
#pragma unroll
                        for (int pj = 0; pj < 4; pj++) {
                            int row = wp * 64 + pj * 16 + lrow;
                            bF[pj] = *(const short8*)(Bs + LDS_SWZ(row, kk * 64 + lk * 16));
                        }
#pragma unroll
                        for (int mi = 0; mi < 2; mi++)
#pragma unroll
                            for (int pj = 0; pj < 4; pj++)
                                acc[mi][pj] = __builtin_amdgcn_mfma_f32_16x16x32_bf16(
                                    aF[mi], bF[pj], acc[mi][pj], 0, 0, 0);
                    }
                    __syncthreads();
                }
                float* pout = part + (size_t)ks * NN * 128;
#pragma unroll
                for (int mi = 0; mi < 2; mi++)
#pragma unroll
                    for (int pj = 0; pj < 4; pj++)
#pragma unroll
                        for (int rr = 0; rr < 4; rr++) {
                            int row = wm * 32 + mi * 16 + (lane >> 4) * 4 + rr;
                            int col = wp * 64 + pj * 16 + (lane & 15);
                            pout[(size_t)(n0 + row) * 128 + col] = acc[mi][pj][rr];
                        }
            }
        }
        grid_barrier(state, NBLK);

        // ---- phase 3: e1 delta = wr[j]*(tanh(sum part + b2) - c_bg) ----
        {
            for (int g = blockIdx.x * 256 + tid; g < NN * 128; g += (int)NBLK * 256) {
                int p = g & 127;
                float s = 0.f;
#pragma unroll
                for (int k = 0; k < KSPLIT; k++) s += part[(size_t)k * NN * 128 + g];
                float c = tanhf(s + b2[p]);
                delta[g] = wr[(g >> 7) & 127] * (c - basics[p]);
            }
        }
        grid_barrier(state, NBLK);

        // ---- phase 4: e2 scatter by heads (+ final root mask at depth 1) ----
        {
            int half = tid >> 7;
            int p = tid & 127;
            float* outp = (depth == 1) ? out : tok;
            for (int u = blockIdx.x; u < 1024; u += (int)NBLK) {
                int bi = u * 2 + half;
                int b = bi >> 7, i = bi & 127;
                hs[half * 128 + p] = heads[b * 128 + p];
                __syncthreads();
                const int* h = hs + half * 128;
                float acc = basics[128 + p];  // base[p]
                for (int j = 0; j < 128; j++) {
                    if (h[j] == i) acc += delta[(size_t)(b * 128 + j) * 128 + p];
                }
                float val = (depth == 1) ? ((h[i] == 0) ? acc : 0.f) : acc;
                outp[(size_t)bi * 128 + p] = val;
                __syncthreads();
            }
        }
        if (depth == 0) grid_barrier(state, NBLK);
    }
}

extern "C" void kernel_launch(void* const* d_in, const int* in_sizes, int n_in,
                              void* d_out, int out_size, void* d_ws, size_t ws_size,
                              hipStream_t stream) {
    const float* token_table = (const float*)d_in[0];
    const float* dep_table   = (const float*)d_in[1];
    const float* W1          = (const float*)d_in[2];
    const float* b1          = (const float*)d_in[3];
    const float* W2          = (const float*)d_in[4];
    const float* b2          = (const float*)d_in[5];
    const float* wr          = (const float*)d_in[6];
    const float* br          = (const float*)d_in[7];
    const int* tokens        = (const int*)d_in[8];
    const int* dep_types     = (const int*)d_in[9];
    const int* dep_heads     = (const int*)d_in[10];
    float* out = (float*)d_out;

    char* ws = (char*)d_ws;
    __hip_bfloat16* G1  = (__hip_bfloat16*)(ws);                      // 2 MB
    __hip_bfloat16* W2b = (__hip_bfloat16*)(ws + (2ull << 20));       // 4 MB
    float* tok    = (float*)(ws + (6ull << 20));                      // 1 MB
    float* tde    = (float*)(ws + (7ull << 20));                      // 1 MB
    float* delta  = (float*)(ws + (8ull << 20));                      // 1 MB
    float* part   = (float*)(ws + (9ull << 20));                      // 16 MB
    float* basics = (float*)(ws + (25ull << 20));                     // 1 KB
    unsigned* state = (unsigned*)(ws + (25ull << 20) + 4096);         // 8 B barrier state

    k_prep<<<2305, 256, 0, stream>>>(W1, dep_table, W2, token_table, tokens,
                                     b2, wr, br, G1, W2b, tok, basics, state);

    // Co-residency check (host-side query; capture-legal). launch_bounds(256,2)
    // + 48KB LDS should give occ>=2 -> grid 512 (2/CU). Fallback 256 (1/CU);
    // both divide every phase's unit count exactly.
    int occ = 0;
    (void)hipOccupancyMaxActiveBlocksPerMultiprocessor(&occ, (const void*)k_mega, 256, 0);
    int grid = (occ >= 2) ? 512 : 256;

    k_mega<<<grid, 256, 0, stream>>>(dep_types, b1, G1, W2b, tok, tde, part,
                                     delta, basics, wr, b2, dep_heads, out, state);
}

// Round 8
// 377.282 us; speedup vs baseline: 1.8042x; 1.8042x over previous
//
#include <hip/hip_runtime.h>
#include <hip/hip_bf16.h>

// Problem constants
#define BB 16
#define SS 128
#define DD 128
#define EE 64
#define TT 128
#define NN (BB*SS)      // 2048 tokens
#define KSPLIT 16       // K split for the big GEMM (d-chunks of 8)

typedef __attribute__((ext_vector_type(8))) short short8;
typedef __attribute__((ext_vector_type(4))) float f32x4;
typedef __attribute__((ext_vector_type(4))) unsigned int u32x4;

__device__ inline unsigned pkbf16(float a, float b) {
    unsigned r;
    asm volatile("v_cvt_pk_bf16_f32 %0, %1, %2" : "=v"(r) : "v"(a), "v"(b));
    return r;
}
__device__ inline float bflo(unsigned u) { return __builtin_bit_cast(float, (unsigned)(u << 16)); }
__device__ inline float bfhi(unsigned u) { return __builtin_bit_cast(float, (unsigned)(u & 0xffff0000u)); }

#define LDS_SWZ(row, bcol) ((row) * 256 + ((bcol) ^ (((row) & 7) << 4)))

// ---------------- fused prep: g1 (64 blk, single W1 pass) + w2b (1024) + gather (1024) + basics/tickets (1) ----------------
__global__ __launch_bounds__(256) void k_prep(const float* __restrict__ W1,
                                              const float* __restrict__ dep_table,
                                              const float* __restrict__ W2,
                                              const float* __restrict__ token_table,
                                              const int* __restrict__ tokens,
                                              const float* __restrict__ b2,
                                              const float* __restrict__ wr,
                                              const float* __restrict__ br,
                                              __hip_bfloat16* __restrict__ G1,
                                              __hip_bfloat16* __restrict__ W2b,
                                              float* __restrict__ tok,
                                              float* __restrict__ basics,
                                              unsigned* __restrict__ tickets) {
    int bid = blockIdx.x;
    int tid = threadIdx.x;
    if (bid < 64) {
        // --- G1[v][t][d] = sum_e W1[t][d][e]*dep_table[v][e] (bf16) ---
        // One block per td-chunk does ALL 64 v in 4 passes; W1 row (256B)
        // stays L1-resident across passes -> W1 fetched from HBM exactly once.
        int td = bid * 256 + tid;  // t*128 + d
        const float* w1row = W1 + (size_t)td * 64;
        for (int vc = 0; vc < 4; vc++) {
            float acc[16] = {};
#pragma unroll
            for (int e0 = 0; e0 < 64; e0 += 8) {
                f32x4 wa = *(const f32x4*)(w1row + e0);
                f32x4 wb = *(const f32x4*)(w1row + e0 + 4);
#pragma unroll
                for (int v = 0; v < 16; v++) {
                    const float* dr = dep_table + (vc * 16 + v) * 64 + e0;  // wave-uniform -> s_load
                    acc[v] += wa[0] * dr[0] + wa[1] * dr[1] + wa[2] * dr[2] + wa[3] * dr[3]
                            + wb[0] * dr[4] + wb[1] * dr[5] + wb[2] * dr[6] + wb[3] * dr[7];
                }
            }
#pragma unroll
            for (int v = 0; v < 16; v++)
                G1[(size_t)(vc * 16 + v) * (TT * DD) + td] = __float2bfloat16(acc[v]);
        }
    } else if (bid < 1088) {
        // --- W2b pre-swizzled bf16: per d, [p=128][256B row], slot s holds t-range (s^(p&7)) ---
        int cid = (bid - 64) * 256 + tid;  // 262144 chunks of 16B
        int d = cid >> 11;
        int rem = cid & 2047;
        int p = rem >> 4;
        int sp = rem & 15;
        int h = sp >> 3, s = sp & 7;
        int t0 = h * 64 + ((s ^ (p & 7))) * 8;
        const float* src = W2 + ((size_t)p * 128 + d) * 128 + t0;  // W2[p][d][t]
        f32x4 a = *(const f32x4*)(src);
        f32x4 b = *(const f32x4*)(src + 4);
        u32x4 o;
        o[0] = pkbf16(a[0], a[1]);
        o[1] = pkbf16(a[2], a[3]);
        o[2] = pkbf16(b[0], b[1]);
        o[3] = pkbf16(b[2], b[3]);
        *(u32x4*)((char*)W2b + (size_t)cid * 16) = o;
    } else if (bid < 2112) {
        // --- gather tok ---
        int gid = (bid - 1088) * 256 + tid;  // 2048*128
        int n = gid >> 7, dcol = gid & 127;
        tok[gid] = token_table[(size_t)tokens[n] * 128 + dcol];
    } else {
        // --- basics: c_bg[p], base[p]; zero split-K tickets (2 depths x 32 tiles) ---
        __shared__ float red[128];
        int t = tid;
        if (t < 64) tickets[t] = 0u;
        if (t < 128) red[t] = wr[t];
        __syncthreads();
        for (int s = 64; s > 0; s >>= 1) {
            if (t < s) red[t] += red[t + s];
            __syncthreads();
        }
        if (t < 128) {
            float swr = red[0];
            float cbg = tanhf(b2[t]);
            basics[t] = cbg;                     // c_bg[p]
            basics[128 + t] = swr * cbg + br[0]; // base[p]
        }
    }
}

// ---------------- tde[n][t] = tanh(sum_d tok[n][d]*G1[v][t][d] + b1[t]) ----------------
__global__ void k_tde(const float* __restrict__ tok, const int* __restrict__ dep_types,
                      const float* __restrict__ b1, const __hip_bfloat16* __restrict__ G1,
                      float* __restrict__ tde) {
    int n = blockIdx.x;
    int t = threadIdx.x;  // 128
    int v = dep_types[n];
    const float* trow = tok + (size_t)n * 128;  // uniform row -> scalar loads
    const unsigned* g = (const unsigned*)(G1 + (size_t)v * (TT * DD) + t * 128);
    float acc = b1[t];
#pragma unroll
    for (int i = 0; i < 16; i++) {
        u32x4 w = *(const u32x4*)(g + i * 4);
        acc += trow[i * 8 + 0] * bflo(w[0]) + trow[i * 8 + 1] * bfhi(w[0]);
        acc += trow[i * 8 + 2] * bflo(w[1]) + trow[i * 8 + 3] * bfhi(w[1]);
        acc += trow[i * 8 + 4] * bflo(w[2]) + trow[i * 8 + 5] * bfhi(w[2]);
        acc += trow[i * 8 + 6] * bflo(w[3]) + trow[i * 8 + 7] * bfhi(w[3]);
    }
    tde[(size_t)n * 128 + t] = tanhf(acc);
}

// ---------------- gemm + fused split-K fixup (e1):
// part[ks][n][p] = sum_{d in chunk, t} tok[n][d]*tde[n][t]*W2[p][d][t]
// Last-arriving block per tile (one-shot ticket, NO polling) reduces the 16
// partials in fixed order 0..15 (bitwise-deterministic), applies tanh, writes
// delta = wr[j]*(c_nz - c_bg). Eliminates the separate k_e1 launch.
__global__ __launch_bounds__(256, 2) void k_gemmf(const float* __restrict__ tok,
                                                  const float* __restrict__ tde,
                                                  const __hip_bfloat16* __restrict__ W2b,
                                                  float* __restrict__ part,
                                                  float* __restrict__ delta,
                                                  const float* __restrict__ basics,
                                                  const float* __restrict__ wr,
                                                  const float* __restrict__ b2,
                                                  unsigned* __restrict__ tickets,
                                                  int dep) {
    __shared__ char As[16384];  // A tile [n=64][k=128t] bf16, swizzled
    __shared__ char Bs[32768];  // B tile [p=128][k=128t] bf16, swizzled (matches W2b layout)
    __shared__ int last;
    int nb = blockIdx.x, ks = blockIdx.y;
    int tid = threadIdx.x;
    int lane = tid & 63, w = tid >> 6;
    int wm = w >> 1, wp = w & 1;        // 2 m-warps x 2 p-warps
    int n0 = nb * 64, d0 = ks * 8;
    int lrow = lane & 15, lk = lane >> 4;
    int r = tid >> 2, q = tid & 3;      // A staging: row r (64 rows), 64B quarter q

    f32x4 acc[2][4] = {};

    for (int dd = 0; dd < 8; dd++) {
        int d = d0 + dd;
        // stage B: linear copy of pre-swizzled 32KB block
        const char* bsrc = (const char*)W2b + (size_t)d * 32768;
#pragma unroll
        for (int i = 0; i < 8; i++) {
            int off = (i * 256 + tid) * 16;
            *(u32x4*)(Bs + off) = *(const u32x4*)(bsrc + off);
        }
        // stage A: products tok[n][d]*tde[n][t], 32 t-values per thread
        float tokv = tok[(size_t)(n0 + r) * 128 + d];
        const float* trow = tde + (size_t)(n0 + r) * 128 + q * 32;
#pragma unroll
        for (int s = 0; s < 4; s++) {
            f32x4 x = *(const f32x4*)(trow + s * 8);
            f32x4 y = *(const f32x4*)(trow + s * 8 + 4);
            u32x4 val;
            val[0] = pkbf16(x[0] * tokv, x[1] * tokv);
            val[1] = pkbf16(x[2] * tokv, x[3] * tokv);
            val[2] = pkbf16(y[0] * tokv, y[1] * tokv);
            val[3] = pkbf16(y[2] * tokv, y[3] * tokv);
            int bcol = q * 64 + s * 16;
            *(u32x4*)(As + LDS_SWZ(r, bcol)) = val;
        }
        __syncthreads();
        // MFMA over 4 k-slices of 32
#pragma unroll
        for (int kk = 0; kk < 4; kk++) {
            short8 aF[2], bF[4];
#pragma unroll
            for (int mi = 0; mi < 2; mi++) {
                int row = wm * 32 + mi * 16 + lrow;
                aF[mi] = *(const short8*)(As + LDS_SWZ(row, kk * 64 + lk * 16));
            }
#pragma unroll
            for (int pj = 0; pj < 4; pj++) {
                int row = wp * 64 + pj * 16 + lrow;
                bF[pj] = *(const short8*)(Bs + LDS_SWZ(row, kk * 64 + lk * 16));
            }
#pragma unroll
            for (int mi = 0; mi < 2; mi++)
#pragma unroll
                for (int pj = 0; pj < 4; pj++)
                    acc[mi][pj] = __builtin_amdgcn_mfma_f32_16x16x32_bf16(
                        aF[mi], bF[pj], acc[mi][pj], 0, 0, 0);
        }
        __syncthreads();
    }
    // write fp32 partials
    float* pout = part + (size_t)ks * NN * 128;
#pragma unroll
    for (int mi = 0; mi < 2; mi++)
#pragma unroll
        for (int pj = 0; pj < 4; pj++)
#pragma unroll
            for (int rr = 0; rr < 4; rr++) {
                int row = wm * 32 + mi * 16 + (lane >> 4) * 4 + rr;
                int col = wp * 64 + pj * 16 + (lane & 15);
                pout[(size_t)(n0 + row) * 128 + col] = acc[mi][pj][rr];
            }

    // ---- split-K fixup (fused e1), one-shot ticket, no polling ----
    __threadfence();      // make this block's part writes agent-visible
    __syncthreads();      // all threads fenced before the release-RMW
    if (tid == 0) {
        unsigned got = __hip_atomic_fetch_add(&tickets[dep * 32 + nb], 1u,
                                              __ATOMIC_ACQ_REL, __HIP_MEMORY_SCOPE_AGENT);
        last = (got == KSPLIT - 1);  // acquire side invalidates stale cache lines
    }
    __syncthreads();
    if (last) {
        for (int pass = 0; pass < 32; pass++) {     // 64 rows x 128 p / 256 thr
            int g = pass * 256 + tid;
            int row = g >> 7, p = g & 127;
            int gg = (n0 + row) * 128 + p;
            float s = 0.f;
#pragma unroll
            for (int k = 0; k < KSPLIT; k++) s += part[(size_t)k * NN * 128 + gg];
            float c = tanhf(s + b2[p]);
            delta[gg] = wr[(n0 + row) & 127] * (c - basics[p]);
        }
    }
}

// ---------------- epilogue 2: scatter by heads; optionally apply final root mask ----------------
__global__ void k_e2(const float* __restrict__ delta, const int* __restrict__ heads,
                     const float* __restrict__ basics, float* __restrict__ outp, int final_mask) {
    int bi = blockIdx.x;  // b*128 + i
    int b = bi >> 7, i = bi & 127;
    int p = threadIdx.x;  // 128
    __shared__ int hs[128];
    hs[p] = heads[b * 128 + p];
    __syncthreads();
    float acc = basics[128 + p];  // base[p]
    for (int j = 0; j < 128; j++) {
        if (hs[j] == i) acc += delta[(size_t)(b * 128 + j) * 128 + p];  // uniform branch
    }
    if (final_mask) {
        outp[(size_t)bi * 128 + p] = (hs[i] == 0) ? acc : 0.f;
    } else {
        outp[(size_t)bi * 128 + p] = acc;
    }
}

extern "C" void kernel_launch(void* const* d_in, const int* in_sizes, int n_in,
                              void* d_out, int out_size, void* d_ws, size_t ws_size,
                              hipStream_t stream) {
    const float* token_table = (const float*)d_in[0];
    const float* dep_table   = (const float*)d_in[1];
    const float* W1          = (const float*)d_in[2];
    const float* b1          = (const float*)d_in[3];
    const float* W2          = (const float*)d_in[4];
    const float* b2          = (const float*)d_in[5];
    const float* wr          = (const float*)d_in[6];
    const float* br          = (const float*)d_in[7];
    const int* tokens        = (const int*)d_in[8];
    const int* dep_types     = (const int*)d_in[9];
    const int* dep_heads     = (const int*)d_in[10];
    float* out = (float*)d_out;

    char* ws = (char*)d_ws;
    __hip_bfloat16* G1  = (__hip_bfloat16*)(ws);                      // 2 MB
    __hip_bfloat16* W2b = (__hip_bfloat16*)(ws + (2ull << 20));       // 4 MB
    float* tok    = (float*)(ws + (6ull << 20));                      // 1 MB
    float* tde    = (float*)(ws + (7ull << 20));                      // 1 MB
    float* delta  = (float*)(ws + (8ull << 20));                      // 1 MB
    float* part   = (float*)(ws + (9ull << 20));                      // 16 MB
    float* basics = (float*)(ws + (25ull << 20));                     // 1 KB
    unsigned* tickets = (unsigned*)(ws + (25ull << 20) + 8192);       // 64 u32

    k_prep<<<2113, 256, 0, stream>>>(W1, dep_table, W2, token_table, tokens,
                                     b2, wr, br, G1, W2b, tok, basics, tickets);

    for (int depth = 0; depth < 2; depth++) {
        k_tde<<<NN, 128, 0, stream>>>(tok, dep_types, b1, G1, tde);
        k_gemmf<<<dim3(32, KSPLIT), 256, 0, stream>>>(tok, tde, W2b, part, delta,
                                                      basics, wr, b2, tickets, depth);
        k_e2<<<NN, 128, 0, stream>>>(delta, dep_heads, basics,
                                     (depth == 1) ? out : tok, depth == 1);
    }
}

// Round 9
// 172.640 us; speedup vs baseline: 3.9428x; 2.1854x over previous
//
#include <hip/hip_runtime.h>
#include <hip/hip_bf16.h>

// Problem constants
#define BB 16
#define SS 128
#define DD 128
#define EE 64
#define TT 128
#define NN (BB*SS)      // 2048 tokens
#define KSPLIT 16       // K split for the big GEMM (d-chunks of 8)

typedef __attribute__((ext_vector_type(8))) short short8;
typedef __attribute__((ext_vector_type(4))) float f32x4;
typedef __attribute__((ext_vector_type(4))) unsigned int u32x4;

__device__ inline unsigned pkbf16(float a, float b) {
    unsigned r;
    asm volatile("v_cvt_pk_bf16_f32 %0, %1, %2" : "=v"(r) : "v"(a), "v"(b));
    return r;
}
__device__ inline float bflo(unsigned u) { return __builtin_bit_cast(float, (unsigned)(u << 16)); }
__device__ inline float bfhi(unsigned u) { return __builtin_bit_cast(float, (unsigned)(u & 0xffff0000u)); }

#define LDS_SWZ(row, bcol) ((row) * 256 + ((bcol) ^ (((row) & 7) << 4)))

// ---------------- prep1: g1 (64 blk, single W1 pass) + w2b (1024) + basics (1) ----------------
__global__ __launch_bounds__(256) void k_prep1(const float* __restrict__ W1,
                                               const float* __restrict__ dep_table,
                                               const float* __restrict__ W2,
                                               const float* __restrict__ b2,
                                               const float* __restrict__ wr,
                                               const float* __restrict__ br,
                                               __hip_bfloat16* __restrict__ G1,
                                               __hip_bfloat16* __restrict__ W2b,
                                               float* __restrict__ basics) {
    int bid = blockIdx.x;
    int tid = threadIdx.x;
    if (bid < 64) {
        // --- G1[v][t][d] = sum_e W1[t][d][e]*dep_table[v][e] (bf16) ---
        // One block per td-chunk does ALL 64 v in 4 passes; W1 row (256B)
        // stays L1-resident across passes -> W1 fetched from HBM once.
        int td = bid * 256 + tid;  // t*128 + d
        const float* w1row = W1 + (size_t)td * 64;
        for (int vc = 0; vc < 4; vc++) {
            float acc[16] = {};
#pragma unroll
            for (int e0 = 0; e0 < 64; e0 += 8) {
                f32x4 wa = *(const f32x4*)(w1row + e0);
                f32x4 wb = *(const f32x4*)(w1row + e0 + 4);
#pragma unroll
                for (int v = 0; v < 16; v++) {
                    const float* dr = dep_table + (vc * 16 + v) * 64 + e0;  // wave-uniform -> s_load
                    acc[v] += wa[0] * dr[0] + wa[1] * dr[1] + wa[2] * dr[2] + wa[3] * dr[3]
                            + wb[0] * dr[4] + wb[1] * dr[5] + wb[2] * dr[6] + wb[3] * dr[7];
                }
            }
#pragma unroll
            for (int v = 0; v < 16; v++)
                G1[(size_t)(vc * 16 + v) * (TT * DD) + td] = __float2bfloat16(acc[v]);
        }
    } else if (bid < 1088) {
        // --- W2b pre-swizzled bf16: per d, [p=128][256B row], slot s holds t-range (s^(p&7)) ---
        int cid = (bid - 64) * 256 + tid;  // 262144 chunks of 16B
        int d = cid >> 11;
        int rem = cid & 2047;
        int p = rem >> 4;
        int sp = rem & 15;
        int h = sp >> 3, s = sp & 7;
        int t0 = h * 64 + ((s ^ (p & 7))) * 8;
        const float* src = W2 + ((size_t)p * 128 + d) * 128 + t0;  // W2[p][d][t]
        f32x4 a = *(const f32x4*)(src);
        f32x4 b = *(const f32x4*)(src + 4);
        u32x4 o;
        o[0] = pkbf16(a[0], a[1]);
        o[1] = pkbf16(a[2], a[3]);
        o[2] = pkbf16(b[0], b[1]);
        o[3] = pkbf16(b[2], b[3]);
        *(u32x4*)((char*)W2b + (size_t)cid * 16) = o;
    } else {
        // --- basics: c_bg[p], base[p] ---
        __shared__ float red[128];
        int t = tid;
        if (t < 128) red[t] = wr[t];
        __syncthreads();
        for (int s = 64; s > 0; s >>= 1) {
            if (t < s) red[t] += red[t + s];
            __syncthreads();
        }
        if (t < 128) {
            float swr = red[0];
            float cbg = tanhf(b2[t]);
            basics[t] = cbg;                     // c_bg[p]
            basics[128 + t] = swr * cbg + br[0]; // base[p]
        }
    }
}

// ---------------- prep2: gather tok (2 rows/block) + fused depth-0 tde ----------------
__global__ __launch_bounds__(256) void k_prep2(const float* __restrict__ token_table,
                                               const int* __restrict__ tokens,
                                               const int* __restrict__ dep_types,
                                               const float* __restrict__ b1,
                                               const __hip_bfloat16* __restrict__ G1,
                                               float* __restrict__ tok,
                                               float* __restrict__ tde) {
    __shared__ float rows[2][128];
    int tid = threadIdx.x;
    int gid = blockIdx.x * 256 + tid;
    int n = gid >> 7, t = tid & 127, half = tid >> 7;
    float val = token_table[(size_t)tokens[n] * 128 + t];
    tok[gid] = val;
    rows[half][t] = val;
    __syncthreads();
    // tde[n][t] = tanh(b1[t] + sum_d rows[half][d]*G1[v][t][d])
    int v = dep_types[n];
    const unsigned* g = (const unsigned*)(G1 + (size_t)v * (TT * DD) + t * 128);
    const float* row = rows[half];
    float acc = b1[t];
#pragma unroll
    for (int i = 0; i < 16; i++) {
        u32x4 w = *(const u32x4*)(g + i * 4);
        acc += row[i * 8 + 0] * bflo(w[0]) + row[i * 8 + 1] * bfhi(w[0]);
        acc += row[i * 8 + 2] * bflo(w[1]) + row[i * 8 + 3] * bfhi(w[1]);
        acc += row[i * 8 + 4] * bflo(w[2]) + row[i * 8 + 5] * bfhi(w[2]);
        acc += row[i * 8 + 6] * bflo(w[3]) + row[i * 8 + 7] * bfhi(w[3]);
    }
    tde[(size_t)n * 128 + t] = tanhf(acc);
}

// ---------------- big GEMM (round-5 version, no fixup):
// part[ks][n][p] = sum_{d in chunk, t} tok[n][d]*tde[n][t]*W2[p][d][t] ----------------
__global__ __launch_bounds__(256) void k_gemm(const float* __restrict__ tok,
                                              const float* __restrict__ tde,
                                              const __hip_bfloat16* __restrict__ W2b,
                                              float* __restrict__ part) {
    __shared__ char As[16384];  // A tile [n=64][k=128t] bf16, swizzled
    __shared__ char Bs[32768];  // B tile [p=128][k=128t] bf16, swizzled (matches W2b layout)
    int nb = blockIdx.x, ks = blockIdx.y;
    int tid = threadIdx.x;
    int lane = tid & 63, w = tid >> 6;
    int wm = w >> 1, wp = w & 1;        // 2 m-warps x 2 p-warps
    int n0 = nb * 64, d0 = ks * 8;
    int lrow = lane & 15, lk = lane >> 4;
    int r = tid >> 2, q = tid & 3;      // A staging: row r (64 rows), 64B quarter q

    f32x4 acc[2][4] = {};

    for (int dd = 0; dd < 8; dd++) {
        int d = d0 + dd;
        // stage B: linear copy of pre-swizzled 32KB block
        const char* bsrc = (const char*)W2b + (size_t)d * 32768;
#pragma unroll
        for (int i = 0; i < 8; i++) {
            int off = (i * 256 + tid) * 16;
            *(u32x4*)(Bs + off) = *(const u32x4*)(bsrc + off);
        }
        // stage A: products tok[n][d]*tde[n][t], 32 t-values per thread
        float tokv = tok[(size_t)(n0 + r) * 128 + d];
        const float* trow = tde + (size_t)(n0 + r) * 128 + q * 32;
#pragma unroll
        for (int s = 0; s < 4; s++) {
            f32x4 x = *(const f32x4*)(trow + s * 8);
            f32x4 y = *(const f32x4*)(trow + s * 8 + 4);
            u32x4 val;
            val[0] = pkbf16(x[0] * tokv, x[1] * tokv);
            val[1] = pkbf16(x[2] * tokv, x[3] * tokv);
            val[2] = pkbf16(y[0] * tokv, y[1] * tokv);
            val[3] = pkbf16(y[2] * tokv, y[3] * tokv);
            int bcol = q * 64 + s * 16;
            *(u32x4*)(As + LDS_SWZ(r, bcol)) = val;
        }
        __syncthreads();
        // MFMA over 4 k-slices of 32
#pragma unroll
        for (int kk = 0; kk < 4; kk++) {
            short8 aF[2], bF[4];
#pragma unroll
            for (int mi = 0; mi < 2; mi++) {
                int row = wm * 32 + mi * 16 + lrow;
                aF[mi] = *(const short8*)(As + LDS_SWZ(row, kk * 64 + lk * 16));
            }
#pragma unroll
            for (int pj = 0; pj < 4; pj++) {
                int row = wp * 64 + pj * 16 + lrow;
                bF[pj] = *(const short8*)(Bs + LDS_SWZ(row, kk * 64 + lk * 16));
            }
#pragma unroll
            for (int mi = 0; mi < 2; mi++)
#pragma unroll
                for (int pj = 0; pj < 4; pj++)
                    acc[mi][pj] = __builtin_amdgcn_mfma_f32_16x16x32_bf16(
                        aF[mi], bF[pj], acc[mi][pj], 0, 0, 0);
        }
        __syncthreads();
    }
    // write fp32 partials
    float* pout = part + (size_t)ks * NN * 128;
#pragma unroll
    for (int mi = 0; mi < 2; mi++)
#pragma unroll
        for (int pj = 0; pj < 4; pj++)
#pragma unroll
            for (int rr = 0; rr < 4; rr++) {
                int row = wm * 32 + mi * 16 + (lane >> 4) * 4 + rr;
                int col = wp * 64 + pj * 16 + (lane & 15);
                pout[(size_t)(n0 + row) * 128 + col] = acc[mi][pj][rr];
            }
}

// ---------------- e2a (depth 0): fused e1 (on-the-fly delta from part) + scatter
// + fused tde for depth 1. Block bi owns output row bi entirely. ----------------
__global__ void k_e2a(const float* __restrict__ part, const int* __restrict__ heads,
                      const float* __restrict__ basics, const float* __restrict__ wr,
                      const float* __restrict__ b2, const int* __restrict__ dep_types,
                      const float* __restrict__ b1, const __hip_bfloat16* __restrict__ G1,
                      float* __restrict__ tok, float* __restrict__ tde) {
    int bi = blockIdx.x;  // b*128 + i
    int b = bi >> 7, i = bi & 127;
    int p = threadIdx.x;  // 128
    __shared__ int hs[128];
    __shared__ float row[128];
    hs[p] = heads[b * 128 + p];
    __syncthreads();
    float cbg = basics[p];
    float acc = basics[128 + p];  // base[p]
    for (int j = 0; j < 128; j++) {
        if (hs[j] == i) {          // block-uniform branch
            int gg = (b * 128 + j) * 128 + p;
            float s = 0.f;
#pragma unroll
            for (int k = 0; k < KSPLIT; k++) s += part[(size_t)k * NN * 128 + gg];
            float c = tanhf(s + b2[p]);
            acc += wr[j] * (c - cbg);
        }
    }
    tok[(size_t)bi * 128 + p] = acc;
    row[p] = acc;
    __syncthreads();
    // tde row bi for the next depth (p doubles as t)
    int v = dep_types[bi];
    const unsigned* g = (const unsigned*)(G1 + (size_t)v * (TT * DD) + p * 128);
    float a2 = b1[p];
#pragma unroll
    for (int ii = 0; ii < 16; ii++) {
        u32x4 w = *(const u32x4*)(g + ii * 4);
        a2 += row[ii * 8 + 0] * bflo(w[0]) + row[ii * 8 + 1] * bfhi(w[0]);
        a2 += row[ii * 8 + 2] * bflo(w[1]) + row[ii * 8 + 3] * bfhi(w[1]);
        a2 += row[ii * 8 + 4] * bflo(w[2]) + row[ii * 8 + 5] * bfhi(w[2]);
        a2 += row[ii * 8 + 6] * bflo(w[3]) + row[ii * 8 + 7] * bfhi(w[3]);
    }
    tde[(size_t)bi * 128 + p] = tanhf(a2);
}

// ---------------- e2b (final): root mask first -> ~99% of blocks just write zeros ----------------
__global__ void k_e2b(const float* __restrict__ part, const int* __restrict__ heads,
                      const float* __restrict__ basics, const float* __restrict__ wr,
                      const float* __restrict__ b2, float* __restrict__ out) {
    int bi = blockIdx.x;  // b*128 + i
    int b = bi >> 7, i = bi & 127;
    int p = threadIdx.x;  // 128
    __shared__ int hs[128];
    hs[p] = heads[b * 128 + p];
    __syncthreads();
    if (hs[i] != 0) {              // masked row: zero and exit
        out[(size_t)bi * 128 + p] = 0.f;
        return;
    }
    float cbg = basics[p];
    float acc = basics[128 + p];
    for (int j = 0; j < 128; j++) {
        if (hs[j] == i) {
            int gg = (b * 128 + j) * 128 + p;
            float s = 0.f;
#pragma unroll
            for (int k = 0; k < KSPLIT; k++) s += part[(size_t)k * NN * 128 + gg];
            float c = tanhf(s + b2[p]);
            acc += wr[j] * (c - cbg);
        }
    }
    out[(size_t)bi * 128 + p] = acc;
}

extern "C" void kernel_launch(void* const* d_in, const int* in_sizes, int n_in,
                              void* d_out, int out_size, void* d_ws, size_t ws_size,
                              hipStream_t stream) {
    const float* token_table = (const float*)d_in[0];
    const float* dep_table   = (const float*)d_in[1];
    const float* W1          = (const float*)d_in[2];
    const float* b1          = (const float*)d_in[3];
    const float* W2          = (const float*)d_in[4];
    const float* b2          = (const float*)d_in[5];
    const float* wr          = (const float*)d_in[6];
    const float* br          = (const float*)d_in[7];
    const int* tokens        = (const int*)d_in[8];
    const int* dep_types     = (const int*)d_in[9];
    const int* dep_heads     = (const int*)d_in[10];
    float* out = (float*)d_out;

    char* ws = (char*)d_ws;
    __hip_bfloat16* G1  = (__hip_bfloat16*)(ws);                      // 2 MB
    __hip_bfloat16* W2b = (__hip_bfloat16*)(ws + (2ull << 20));       // 4 MB
    float* tok    = (float*)(ws + (6ull << 20));                      // 1 MB
    float* tde    = (float*)(ws + (7ull << 20));                      // 1 MB
    float* part   = (float*)(ws + (9ull << 20));                      // 16 MB
    float* basics = (float*)(ws + (25ull << 20));                     // 1 KB

    k_prep1<<<1089, 256, 0, stream>>>(W1, dep_table, W2, b2, wr, br, G1, W2b, basics);
    k_prep2<<<1024, 256, 0, stream>>>(token_table, tokens, dep_types, b1, G1, tok, tde);

    // depth 0
    k_gemm<<<dim3(32, KSPLIT), 256, 0, stream>>>(tok, tde, W2b, part);
    k_e2a<<<NN, 128, 0, stream>>>(part, dep_heads, basics, wr, b2,
                                  dep_types, b1, G1, tok, tde);
    // depth 1
    k_gemm<<<dim3(32, KSPLIT), 256, 0, stream>>>(tok, tde, W2b, part);
    k_e2b<<<NN, 128, 0, stream>>>(part, dep_heads, basics, wr, b2, out);
}

// Round 10
// 116.697 us; speedup vs baseline: 5.8329x; 1.4794x over previous
//
#include <hip/hip_runtime.h>
#include <hip/hip_bf16.h>

// Problem constants
#define BB 16
#define SS 128
#define DD 128
#define EE 64
#define TT 128
#define NN (BB*SS)      // 2048 tokens
#define KSPLIT 16       // K split for the big GEMM (d-chunks of 8)

typedef __attribute__((ext_vector_type(8))) short short8;
typedef __attribute__((ext_vector_type(4))) float f32x4;
typedef __attribute__((ext_vector_type(4))) unsigned int u32x4;

__device__ inline unsigned pkbf16(float a, float b) {
    unsigned r;
    asm volatile("v_cvt_pk_bf16_f32 %0, %1, %2" : "=v"(r) : "v"(a), "v"(b));
    return r;
}
__device__ inline float bflo(unsigned u) { return __builtin_bit_cast(float, (unsigned)(u << 16)); }
__device__ inline float bfhi(unsigned u) { return __builtin_bit_cast(float, (unsigned)(u & 0xffff0000u)); }

#define LDS_SWZ(row, bcol) ((row) * 256 + ((bcol) ^ (((row) & 7) << 4)))

// ---------------- prep1: g1 (512 blk: 64 td-chunks x 8 v-groups) + w2b (1024) + basics (1) ----------------
// Round-9 lesson: 64-block G1 with serial v-passes = 1 wave/SIMD latency-bound
// straggler (80us). Parallelize v across blocks instead; W1 re-fetch is L3-hit.
__global__ __launch_bounds__(256) void k_prep1(const float* __restrict__ W1,
                                               const float* __restrict__ dep_table,
                                               const float* __restrict__ W2,
                                               const float* __restrict__ b2,
                                               const float* __restrict__ wr,
                                               const float* __restrict__ br,
                                               __hip_bfloat16* __restrict__ G1,
                                               __hip_bfloat16* __restrict__ W2b,
                                               float* __restrict__ basics) {
    int bid = blockIdx.x;
    int tid = threadIdx.x;
    if (bid < 512) {
        // --- G1[v][t][d] = sum_e W1[t][d][e]*dep_table[v][e] (bf16) ---
        int bx = bid & 63, by = bid >> 6;
        int td = bx * 256 + tid;  // t*128 + d
        int v0 = by * 8;          // 8 v per block
        const float* w1row = W1 + (size_t)td * 64;
        float acc[8] = {};
#pragma unroll
        for (int e0 = 0; e0 < 64; e0 += 8) {
            f32x4 wa = *(const f32x4*)(w1row + e0);
            f32x4 wb = *(const f32x4*)(w1row + e0 + 4);
#pragma unroll
            for (int v = 0; v < 8; v++) {
                const float* dr = dep_table + (v0 + v) * 64 + e0;  // wave-uniform -> s_load
                acc[v] += wa[0] * dr[0] + wa[1] * dr[1] + wa[2] * dr[2] + wa[3] * dr[3]
                        + wb[0] * dr[4] + wb[1] * dr[5] + wb[2] * dr[6] + wb[3] * dr[7];
            }
        }
#pragma unroll
        for (int v = 0; v < 8; v++)
            G1[(size_t)(v0 + v) * (TT * DD) + td] = __float2bfloat16(acc[v]);
    } else if (bid < 1536) {
        // --- W2b pre-swizzled bf16: per d, [p=128][256B row], slot s holds t-range (s^(p&7)) ---
        int cid = (bid - 512) * 256 + tid;  // 262144 chunks of 16B
        int d = cid >> 11;
        int rem = cid & 2047;
        int p = rem >> 4;
        int sp = rem & 15;
        int h = sp >> 3, s = sp & 7;
        int t0 = h * 64 + ((s ^ (p & 7))) * 8;
        const float* src = W2 + ((size_t)p * 128 + d) * 128 + t0;  // W2[p][d][t]
        f32x4 a = *(const f32x4*)(src);
        f32x4 b = *(const f32x4*)(src + 4);
        u32x4 o;
        o[0] = pkbf16(a[0], a[1]);
        o[1] = pkbf16(a[2], a[3]);
        o[2] = pkbf16(b[0], b[1]);
        o[3] = pkbf16(b[2], b[3]);
        *(u32x4*)((char*)W2b + (size_t)cid * 16) = o;
    } else {
        // --- basics: c_bg[p], base[p] ---
        __shared__ float red[128];
        int t = tid;
        if (t < 128) red[t] = wr[t];
        __syncthreads();
        for (int s = 64; s > 0; s >>= 1) {
            if (t < s) red[t] += red[t + s];
            __syncthreads();
        }
        if (t < 128) {
            float swr = red[0];
            float cbg = tanhf(b2[t]);
            basics[t] = cbg;                     // c_bg[p]
            basics[128 + t] = swr * cbg + br[0]; // base[p]
        }
    }
}

// ---------------- prep2: gather tok (2 rows/block) + fused depth-0 tde ----------------
__global__ __launch_bounds__(256) void k_prep2(const float* __restrict__ token_table,
                                               const int* __restrict__ tokens,
                                               const int* __restrict__ dep_types,
                                               const float* __restrict__ b1,
                                               const __hip_bfloat16* __restrict__ G1,
                                               float* __restrict__ tok,
                                               float* __restrict__ tde) {
    __shared__ float rows[2][128];
    int tid = threadIdx.x;
    int gid = blockIdx.x * 256 + tid;
    int n = gid >> 7, t = tid & 127, half = tid >> 7;
    float val = token_table[(size_t)tokens[n] * 128 + t];
    tok[gid] = val;
    rows[half][t] = val;
    __syncthreads();
    // tde[n][t] = tanh(b1[t] + sum_d rows[half][d]*G1[v][t][d])
    int v = dep_types[n];
    const unsigned* g = (const unsigned*)(G1 + (size_t)v * (TT * DD) + t * 128);
    const float* row = rows[half];
    float acc = b1[t];
#pragma unroll
    for (int i = 0; i < 16; i++) {
        u32x4 w = *(const u32x4*)(g + i * 4);
        acc += row[i * 8 + 0] * bflo(w[0]) + row[i * 8 + 1] * bfhi(w[0]);
        acc += row[i * 8 + 2] * bflo(w[1]) + row[i * 8 + 3] * bfhi(w[1]);
        acc += row[i * 8 + 4] * bflo(w[2]) + row[i * 8 + 5] * bfhi(w[2]);
        acc += row[i * 8 + 6] * bflo(w[3]) + row[i * 8 + 7] * bfhi(w[3]);
    }
    tde[(size_t)n * 128 + t] = tanhf(acc);
}

// ---------------- big GEMM: part[ks][n][p] = sum_{d in chunk, t} tok[n][d]*tde[n][t]*W2[p][d][t] ----------------
__global__ __launch_bounds__(256) void k_gemm(const float* __restrict__ tok,
                                              const float* __restrict__ tde,
                                              const __hip_bfloat16* __restrict__ W2b,
                                              float* __restrict__ part) {
    __shared__ char As[16384];  // A tile [n=64][k=128t] bf16, swizzled
    __shared__ char Bs[32768];  // B tile [p=128][k=128t] bf16, swizzled (matches W2b layout)
    int nb = blockIdx.x, ks = blockIdx.y;
    int tid = threadIdx.x;
    int lane = tid & 63, w = tid >> 6;
    int wm = w >> 1, wp = w & 1;        // 2 m-warps x 2 p-warps
    int n0 = nb * 64, d0 = ks * 8;
    int lrow = lane & 15, lk = lane >> 4;
    int r = tid >> 2, q = tid & 3;      // A staging: row r (64 rows), 64B quarter q

    f32x4 acc[2][4] = {};

    for (int dd = 0; dd < 8; dd++) {
        int d = d0 + dd;
        // stage B: linear copy of pre-swizzled 32KB block
        const char* bsrc = (const char*)W2b + (size_t)d * 32768;
#pragma unroll
        for (int i = 0; i < 8; i++) {
            int off = (i * 256 + tid) * 16;
            *(u32x4*)(Bs + off) = *(const u32x4*)(bsrc + off);
        }
        // stage A: products tok[n][d]*tde[n][t], 32 t-values per thread
        float tokv = tok[(size_t)(n0 + r) * 128 + d];
        const float* trow = tde + (size_t)(n0 + r) * 128 + q * 32;
#pragma unroll
        for (int s = 0; s < 4; s++) {
            f32x4 x = *(const f32x4*)(trow + s * 8);
            f32x4 y = *(const f32x4*)(trow + s * 8 + 4);
            u32x4 val;
            val[0] = pkbf16(x[0] * tokv, x[1] * tokv);
            val[1] = pkbf16(x[2] * tokv, x[3] * tokv);
            val[2] = pkbf16(y[0] * tokv, y[1] * tokv);
            val[3] = pkbf16(y[2] * tokv, y[3] * tokv);
            int bcol = q * 64 + s * 16;
            *(u32x4*)(As + LDS_SWZ(r, bcol)) = val;
        }
        __syncthreads();
        // MFMA over 4 k-slices of 32
#pragma unroll
        for (int kk = 0; kk < 4; kk++) {
            short8 aF[2], bF[4];
#pragma unroll
            for (int mi = 0; mi < 2; mi++) {
                int row = wm * 32 + mi * 16 + lrow;
                aF[mi] = *(const short8*)(As + LDS_SWZ(row, kk * 64 + lk * 16));
            }
#pragma unroll
            for (int pj = 0; pj < 4; pj++) {
                int row = wp * 64 + pj * 16 + lrow;
                bF[pj] = *(const short8*)(Bs + LDS_SWZ(row, kk * 64 + lk * 16));
            }
#pragma unroll
            for (int mi = 0; mi < 2; mi++)
#pragma unroll
                for (int pj = 0; pj < 4; pj++)
                    acc[mi][pj] = __builtin_amdgcn_mfma_f32_16x16x32_bf16(
                        aF[mi], bF[pj], acc[mi][pj], 0, 0, 0);
        }
        __syncthreads();
    }
    // write fp32 partials
    float* pout = part + (size_t)ks * NN * 128;
#pragma unroll
    for (int mi = 0; mi < 2; mi++)
#pragma unroll
        for (int pj = 0; pj < 4; pj++)
#pragma unroll
            for (int rr = 0; rr < 4; rr++) {
                int row = wm * 32 + mi * 16 + (lane >> 4) * 4 + rr;
                int col = wp * 64 + pj * 16 + (lane & 15);
                pout[(size_t)(n0 + row) * 128 + col] = acc[mi][pj][rr];
            }
}

// ---------------- e2a (depth 0): fused e1 (on-the-fly delta from part) + scatter
// + fused tde for depth 1. Block bi owns output row bi entirely. ----------------
__global__ void k_e2a(const float* __restrict__ part, const int* __restrict__ heads,
                      const float* __restrict__ basics, const float* __restrict__ wr,
                      const float* __restrict__ b2, const int* __restrict__ dep_types,
                      const float* __restrict__ b1, const __hip_bfloat16* __restrict__ G1,
                      float* __restrict__ tok, float* __restrict__ tde) {
    int bi = blockIdx.x;  // b*128 + i
    int b = bi >> 7, i = bi & 127;
    int p = threadIdx.x;  // 128
    __shared__ int hs[128];
    __shared__ float row[128];
    hs[p] = heads[b * 128 + p];
    __syncthreads();
    float cbg = basics[p];
    float acc = basics[128 + p];  // base[p]
    for (int j = 0; j < 128; j++) {
        if (hs[j] == i) {          // block-uniform branch
            int gg = (b * 128 + j) * 128 + p;
            float s = 0.f;
#pragma unroll
            for (int k = 0; k < KSPLIT; k++) s += part[(size_t)k * NN * 128 + gg];
            float c = tanhf(s + b2[p]);
            acc += wr[j] * (c - cbg);
        }
    }
    tok[(size_t)bi * 128 + p] = acc;
    row[p] = acc;
    __syncthreads();
    // tde row bi for the next depth (p doubles as t)
    int v = dep_types[bi];
    const unsigned* g = (const unsigned*)(G1 + (size_t)v * (TT * DD) + p * 128);
    float a2 = b1[p];
#pragma unroll
    for (int ii = 0; ii < 16; ii++) {
        u32x4 w = *(const u32x4*)(g + ii * 4);
        a2 += row[ii * 8 + 0] * bflo(w[0]) + row[ii * 8 + 1] * bfhi(w[0]);
        a2 += row[ii * 8 + 2] * bflo(w[1]) + row[ii * 8 + 3] * bfhi(w[1]);
        a2 += row[ii * 8 + 4] * bflo(w[2]) + row[ii * 8 + 5] * bfhi(w[2]);
        a2 += row[ii * 8 + 6] * bflo(w[3]) + row[ii * 8 + 7] * bfhi(w[3]);
    }
    tde[(size_t)bi * 128 + p] = tanhf(a2);
}

// ---------------- e2b (final): root mask first -> ~99% of blocks just write zeros ----------------
__global__ void k_e2b(const float* __restrict__ part, const int* __restrict__ heads,
                      const float* __restrict__ basics, const float* __restrict__ wr,
                      const float* __restrict__ b2, float* __restrict__ out) {
    int bi = blockIdx.x;  // b*128 + i
    int b = bi >> 7, i = bi & 127;
    int p = threadIdx.x;  // 128
    __shared__ int hs[128];
    hs[p] = heads[b * 128 + p];
    __syncthreads();
    if (hs[i] != 0) {              // masked row: zero and exit
        out[(size_t)bi * 128 + p] = 0.f;
        return;
    }
    float cbg = basics[p];
    float acc = basics[128 + p];
    for (int j = 0; j < 128; j++) {
        if (hs[j] == i) {
            int gg = (b * 128 + j) * 128 + p;
            float s = 0.f;
#pragma unroll
            for (int k = 0; k < KSPLIT; k++) s += part[(size_t)k * NN * 128 + gg];
            float c = tanhf(s + b2[p]);
            acc += wr[j] * (c - cbg);
        }
    }
    out[(size_t)bi * 128 + p] = acc;
}

extern "C" void kernel_launch(void* const* d_in, const int* in_sizes, int n_in,
                              void* d_out, int out_size, void* d_ws, size_t ws_size,
                              hipStream_t stream) {
    const float* token_table = (const float*)d_in[0];
    const float* dep_table   = (const float*)d_in[1];
    const float* W1          = (const float*)d_in[2];
    const float* b1          = (const float*)d_in[3];
    const float* W2          = (const float*)d_in[4];
    const float* b2          = (const float*)d_in[5];
    const float* wr          = (const float*)d_in[6];
    const float* br          = (const float*)d_in[7];
    const int* tokens        = (const int*)d_in[8];
    const int* dep_types     = (const int*)d_in[9];
    const int* dep_heads     = (const int*)d_in[10];
    float* out = (float*)d_out;

    char* ws = (char*)d_ws;
    __hip_bfloat16* G1  = (__hip_bfloat16*)(ws);                      // 2 MB
    __hip_bfloat16* W2b = (__hip_bfloat16*)(ws + (2ull << 20));       // 4 MB
    float* tok    = (float*)(ws + (6ull << 20));                      // 1 MB
    float* tde    = (float*)(ws + (7ull << 20));                      // 1 MB
    float* part   = (float*)(ws + (9ull << 20));                      // 16 MB
    float* basics = (float*)(ws + (25ull << 20));                     // 1 KB

    k_prep1<<<1537, 256, 0, stream>>>(W1, dep_table, W2, b2, wr, br, G1, W2b, basics);
    k_prep2<<<1024, 256, 0, stream>>>(token_table, tokens, dep_types, b1, G1, tok, tde);

    // depth 0
    k_gemm<<<dim3(32, KSPLIT), 256, 0, stream>>>(tok, tde, W2b, part);
    k_e2a<<<NN, 128, 0, stream>>>(part, dep_heads, basics, wr, b2,
                                  dep_types, b1, G1, tok, tde);
    // depth 1
    k_gemm<<<dim3(32, KSPLIT), 256, 0, stream>>>(tok, tde, W2b, part);
    k_e2b<<<NN, 128, 0, stream>>>(part, dep_heads, basics, wr, b2, out);
}